// Round 1
// baseline (1212.732 us; speedup 1.0000x reference)
//
#include <hip/hip_runtime.h>

#define LSEQ 2048
#define HDIM 2048
#define NHEAD 16
#define DHEAD 128
#define N1 14336   // 3H + MLP
#define NC 10240   // H + MLP

typedef unsigned short u16;
typedef __attribute__((ext_vector_type(8))) short short8;
typedef __attribute__((ext_vector_type(4))) float f32x4;

#define ASYNC16(g, l) __builtin_amdgcn_global_load_lds( \
    (__attribute__((address_space(1))) void*)(g),        \
    (__attribute__((address_space(3))) void*)(l), 16, 0, 0)

__device__ __forceinline__ u16 f2bf(float f) {
  unsigned u = __builtin_bit_cast(unsigned, f);
  u += 0x7fffu + ((u >> 16) & 1u);
  return (u16)(u >> 16);
}
__device__ __forceinline__ float bf2f(u16 v) {
  unsigned u = ((unsigned)v) << 16;
  return __builtin_bit_cast(float, u);
}
__device__ __forceinline__ float silu_f(float x) { return x / (1.f + __expf(-x)); }
__device__ __forceinline__ float gelu_f(float x) {
  float u = 0.7978845608028654f * (x + 0.044715f * x * x * x);
  float e = __expf(2.f * u);
  float th = 1.f - 2.f / (e + 1.f);
  return 0.5f * x * (1.f + th);
}

// ---------------- mod = silu(vec) @ mod_w.T + mod_b ----------------
__global__ __launch_bounds__(256) void k_mod(const float* __restrict__ vec,
                                             const float* __restrict__ mod_w,
                                             const float* __restrict__ mod_b,
                                             float* __restrict__ modv) {
  int j = blockIdx.x, t = threadIdx.x;
  const float4* wr = (const float4*)(mod_w + (size_t)j * HDIM);
  const float4* vv = (const float4*)vec;
  float s0 = 0.f, s1 = 0.f;
#pragma unroll
  for (int i = 0; i < 2; i++) {
    int idx = t + i * 256;
    float4 w = wr[idx];
    float4 a = vv[idx];
    float4 c = vv[idx + 512];
    s0 += w.x*silu_f(a.x) + w.y*silu_f(a.y) + w.z*silu_f(a.z) + w.w*silu_f(a.w);
    s1 += w.x*silu_f(c.x) + w.y*silu_f(c.y) + w.z*silu_f(c.z) + w.w*silu_f(c.w);
  }
  int lane = t & 63, wid = t >> 6;
#pragma unroll
  for (int o = 32; o; o >>= 1) { s0 += __shfl_down(s0, o, 64); s1 += __shfl_down(s1, o, 64); }
  __shared__ float red[8];
  if (!lane) { red[wid] = s0; red[4 + wid] = s1; }
  __syncthreads();
  if (!t) {
    float b_ = mod_b[j];
    modv[j] = red[0]+red[1]+red[2]+red[3] + b_;
    modv[3*HDIM + j] = red[4]+red[5]+red[6]+red[7] + b_;
  }
}

// ---------------- x_mod = (1+scale)*LN(x) + shift, bf16 ----------------
__global__ __launch_bounds__(256) void k_ln(const float* __restrict__ x,
                                            const float* __restrict__ modv,
                                            u16* __restrict__ xmod) {
  int row = blockIdx.x, t = threadIdx.x;
  int b = row >> 11;
  const float4* xr = (const float4*)(x + (size_t)row * HDIM);
  float4 v0 = xr[t], v1 = xr[t + 256];
  float sum = v0.x+v0.y+v0.z+v0.w + v1.x+v1.y+v1.z+v1.w;
  float sq  = v0.x*v0.x+v0.y*v0.y+v0.z*v0.z+v0.w*v0.w
            + v1.x*v1.x+v1.y*v1.y+v1.z*v1.z+v1.w*v1.w;
  int lane = t & 63, wid = t >> 6;
#pragma unroll
  for (int o = 32; o; o >>= 1) { sum += __shfl_down(sum, o, 64); sq += __shfl_down(sq, o, 64); }
  __shared__ float red[8];
  if (!lane) { red[wid] = sum; red[4+wid] = sq; }
  __syncthreads();
  sum = red[0]+red[1]+red[2]+red[3];
  sq  = red[4]+red[5]+red[6]+red[7];
  float mu = sum * (1.f/HDIM);
  float rstd = rsqrtf(sq * (1.f/HDIM) - mu*mu + 1e-6f);
  const float* mb = modv + b * (3*HDIM);
  u16* orow = xmod + (size_t)row * HDIM;
  float vv[8] = {v0.x,v0.y,v0.z,v0.w,v1.x,v1.y,v1.z,v1.w};
#pragma unroll
  for (int half = 0; half < 2; half++) {
    int h0 = (t + half*256) * 4;
    ushort4 o4;
    float e0 = (1.f + mb[HDIM + h0+0]) * ((vv[half*4+0]-mu)*rstd) + mb[h0+0];
    float e1 = (1.f + mb[HDIM + h0+1]) * ((vv[half*4+1]-mu)*rstd) + mb[h0+1];
    float e2 = (1.f + mb[HDIM + h0+2]) * ((vv[half*4+2]-mu)*rstd) + mb[h0+2];
    float e3 = (1.f + mb[HDIM + h0+3]) * ((vv[half*4+3]-mu)*rstd) + mb[h0+3];
    o4.x = f2bf(e0); o4.y = f2bf(e1); o4.z = f2bf(e2); o4.w = f2bf(e3);
    *(ushort4*)(orow + h0) = o4;
  }
}

// ---------------- f32 -> bf16 weight convert ----------------
__global__ __launch_bounds__(256) void k_cvt(const float4* __restrict__ src,
                                             ushort4* __restrict__ dst, int n4) {
  int i = blockIdx.x * 256 + threadIdx.x;
  int stride = gridDim.x * 256;
  for (; i < n4; i += stride) {
    float4 v = src[i];
    ushort4 o;
    o.x = f2bf(v.x); o.y = f2bf(v.y); o.z = f2bf(v.z); o.w = f2bf(v.w);
    dst[i] = o;
  }
}

// ---------------- GEMM1: h = xmod @ W1^T + b1 ; split qkv / gelu(mlp) ----------------
__global__ __launch_bounds__(256, 2) void k_gemm1(const u16* __restrict__ A,
                                                  const u16* __restrict__ Bw,
                                                  const float* __restrict__ bias,
                                                  u16* __restrict__ qkv,
                                                  u16* __restrict__ cat) {
  const int K = HDIM;
  const int NB = N1 / 128;  // 112
  int bid = blockIdx.x;
  int bm = bid / NB, bn = bid % NB;
  int t = threadIdx.x, wave = t >> 6, lane = t & 63;
  int wm = wave >> 1, wn = wave & 1;
  __shared__ u16 As[128 * 32];
  __shared__ u16 Bs[128 * 32];
  const f32x4 fzero = {0.f, 0.f, 0.f, 0.f};
  f32x4 acc[4][4];
#pragma unroll
  for (int i = 0; i < 4; i++)
#pragma unroll
    for (int j2 = 0; j2 < 4; j2++) acc[i][j2] = fzero;
  const u16* Ab = A + (size_t)bm * 128 * K;
  const u16* Bb = Bw + (size_t)bn * 128 * K;
  int r4 = lane >> 2, c4 = lane & 3;
  int fm = lane & 15, fk = (lane >> 4) * 8;
  for (int k0 = 0; k0 < K; k0 += 32) {
#pragma unroll
    for (int i = 0; i < 2; i++) {
      int row = wave*32 + i*16;
      ASYNC16(Ab + (size_t)(row + r4)*K + k0 + c4*8, &As[row*32]);
      ASYNC16(Bb + (size_t)(row + r4)*K + k0 + c4*8, &Bs[row*32]);
    }
    __syncthreads();
    short8 af[4], bfr[4];
#pragma unroll
    for (int mt = 0; mt < 4; mt++)
      af[mt] = *(const short8*)&As[(wm*64 + mt*16 + fm)*32 + fk];
#pragma unroll
    for (int nt = 0; nt < 4; nt++)
      bfr[nt] = *(const short8*)&Bs[(wn*64 + nt*16 + fm)*32 + fk];
#pragma unroll
    for (int mt = 0; mt < 4; mt++)
#pragma unroll
      for (int nt = 0; nt < 4; nt++)
        acc[mt][nt] = __builtin_amdgcn_mfma_f32_16x16x32_bf16(af[mt], bfr[nt], acc[mt][nt], 0, 0, 0);
    __syncthreads();
  }
  int rbase = bm*128 + wm*64;
  int cbase = bn*128 + wn*64;
#pragma unroll
  for (int nt = 0; nt < 4; nt++) {
    int col = cbase + nt*16 + fm;
    float bv = bias[col];
    bool isqkv = (col < 3*HDIM);
#pragma unroll
    for (int mt = 0; mt < 4; mt++) {
#pragma unroll
      for (int rr = 0; rr < 4; rr++) {
        int row = rbase + mt*16 + (lane>>4)*4 + rr;
        float v = acc[mt][nt][rr] + bv;
        if (isqkv) qkv[(size_t)row*(3*HDIM) + col] = f2bf(v);
        else       cat[(size_t)row*NC + HDIM + (col - 3*HDIM)] = f2bf(gelu_f(v));
      }
    }
  }
}

// ---------------- GEMM2: out = x + gate*(cat @ W2^T + b2) ----------------
__global__ __launch_bounds__(256, 2) void k_gemm2(const u16* __restrict__ A,
                                                  const u16* __restrict__ Bw,
                                                  const float* __restrict__ bias,
                                                  const float* __restrict__ xres,
                                                  const float* __restrict__ modv,
                                                  float* __restrict__ out) {
  const int K = NC;
  const int NB = HDIM / 128;  // 16
  int bid = blockIdx.x;
  int bm = bid / NB, bn = bid % NB;
  int t = threadIdx.x, wave = t >> 6, lane = t & 63;
  int wm = wave >> 1, wn = wave & 1;
  __shared__ u16 As[128 * 32];
  __shared__ u16 Bs[128 * 32];
  const f32x4 fzero = {0.f, 0.f, 0.f, 0.f};
  f32x4 acc[4][4];
#pragma unroll
  for (int i = 0; i < 4; i++)
#pragma unroll
    for (int j2 = 0; j2 < 4; j2++) acc[i][j2] = fzero;
  const u16* Ab = A + (size_t)bm * 128 * K;
  const u16* Bb = Bw + (size_t)bn * 128 * K;
  int r4 = lane >> 2, c4 = lane & 3;
  int fm = lane & 15, fk = (lane >> 4) * 8;
  for (int k0 = 0; k0 < K; k0 += 32) {
#pragma unroll
    for (int i = 0; i < 2; i++) {
      int row = wave*32 + i*16;
      ASYNC16(Ab + (size_t)(row + r4)*K + k0 + c4*8, &As[row*32]);
      ASYNC16(Bb + (size_t)(row + r4)*K + k0 + c4*8, &Bs[row*32]);
    }
    __syncthreads();
    short8 af[4], bfr[4];
#pragma unroll
    for (int mt = 0; mt < 4; mt++)
      af[mt] = *(const short8*)&As[(wm*64 + mt*16 + fm)*32 + fk];
#pragma unroll
    for (int nt = 0; nt < 4; nt++)
      bfr[nt] = *(const short8*)&Bs[(wn*64 + nt*16 + fm)*32 + fk];
#pragma unroll
    for (int mt = 0; mt < 4; mt++)
#pragma unroll
      for (int nt = 0; nt < 4; nt++)
        acc[mt][nt] = __builtin_amdgcn_mfma_f32_16x16x32_bf16(af[mt], bfr[nt], acc[mt][nt], 0, 0, 0);
    __syncthreads();
  }
  int rbase = bm*128 + wm*64;
  int cbase = bn*128 + wn*64;
  int b = (bm*128) >> 11;   // blocks never straddle batch boundary (2048 % 128 == 0)
#pragma unroll
  for (int nt = 0; nt < 4; nt++) {
    int col = cbase + nt*16 + fm;
    float bv = bias[col];
    float g = modv[b*(3*HDIM) + 2*HDIM + col];
#pragma unroll
    for (int mt = 0; mt < 4; mt++) {
#pragma unroll
      for (int rr = 0; rr < 4; rr++) {
        int row = rbase + mt*16 + (lane>>4)*4 + rr;
        size_t idx = (size_t)row*HDIM + col;
        out[idx] = xres[idx] + g * (acc[mt][nt][rr] + bv);
      }
    }
  }
}

// ---------------- q,k: rmsnorm + rope -> Q,K (b,h,l,d) bf16 ----------------
__global__ __launch_bounds__(128) void k_qk(const u16* __restrict__ qkv,
                                            const float* __restrict__ pe,
                                            const float* __restrict__ q_scale,
                                            const float* __restrict__ k_scale,
                                            u16* __restrict__ Q, u16* __restrict__ Ko) {
  int bid = blockIdx.x;
  int l = bid & (LSEQ-1);
  int h = (bid >> 11) & (NHEAD-1);
  int b = bid >> 15;
  int d = threadIdx.x;
  const u16* base = qkv + ((size_t)(b*LSEQ + l)) * (3*HDIM);
  float qv = bf2f(base[h*DHEAD + d]);
  float kv = bf2f(base[HDIM + h*DHEAD + d]);
  float sq = qv*qv, sk = kv*kv;
  int lane = d & 63, wid = d >> 6;
#pragma unroll
  for (int o = 32; o; o >>= 1) { sq += __shfl_down(sq, o, 64); sk += __shfl_down(sk, o, 64); }
  __shared__ float red[4];
  __shared__ float qn[128], kn[128];
  if (!lane) { red[wid] = sq; red[2+wid] = sk; }
  __syncthreads();
  float rq = rsqrtf((red[0]+red[1]) * (1.f/DHEAD) + 1e-6f);
  float rk = rsqrtf((red[2]+red[3]) * (1.f/DHEAD) + 1e-6f);
  qn[d] = qv * rq * q_scale[d];
  kn[d] = kv * rk * k_scale[d];
  __syncthreads();
  int p = d >> 1, j = d & 1;
  const float2 pp = *(const float2*)(pe + (((size_t)(b*LSEQ + l))*64 + p)*4 + j*2);
  float qo = pp.x * qn[2*p] + pp.y * qn[2*p+1];
  float ko = pp.x * kn[2*p] + pp.y * kn[2*p+1];
  size_t oidx = (((size_t)(b*NHEAD + h))*LSEQ + l)*DHEAD + d;
  Q[oidx]  = f2bf(qo);
  Ko[oidx] = f2bf(ko);
}

// ---------------- V transpose: qkv v-part -> Vt (b,h,d,l) bf16 ----------------
__global__ __launch_bounds__(256) void k_vt(const u16* __restrict__ qkv, u16* __restrict__ Vt) {
  int bid = blockIdx.x;
  int lt = bid & 31, h = (bid >> 5) & 15, b = bid >> 9;
  __shared__ u16 tile[64][132];
  int t = threadIdx.x;
#pragma unroll
  for (int it = 0; it < 8; it++) {
    int idx = it*1024 + t*4;
    int li = idx >> 7, di = idx & 127;
    const u16* src = qkv + ((size_t)(b*LSEQ + lt*64 + li))*(3*HDIM) + 2*HDIM + h*DHEAD + di;
    ushort4 v = *(const ushort4*)src;
    *(ushort4*)&tile[li][di] = v;
  }
  __syncthreads();
  u16* dst = Vt + ((size_t)(b*NHEAD + h))*DHEAD*LSEQ + lt*64;
#pragma unroll
  for (int it = 0; it < 32; it++) {
    int idx = it*256 + t;
    int lo = idx & 63, dd = idx >> 6;
    dst[(size_t)dd*LSEQ + lo] = tile[lo][dd];
  }
}

// ---------------- flash attention ----------------
#define ATT_SCALE 0.08838834764831845f
__global__ __launch_bounds__(256, 2) void k_attn(const u16* __restrict__ Q,
                                                 const u16* __restrict__ Kc,
                                                 const u16* __restrict__ Vt,
                                                 u16* __restrict__ cat) {
  __shared__ u16 Qs[64*128];
  __shared__ u16 Ks[64*128];
  __shared__ u16 Vs[128*64];
  __shared__ u16 Ps[64*72];
  int bid = blockIdx.x;
  int qt = bid & 31, h = (bid >> 5) & 15, b = bid >> 9;
  int t = threadIdx.x, wave = t >> 6, lane = t & 63;
  int fm = lane & 15, fq = lane >> 4;
  int r8 = lane >> 3, c8 = lane & 7;
  const u16* Qg = Q  + (((size_t)(b*NHEAD + h))*LSEQ + qt*64) * DHEAD;
  const u16* Kg = Kc + ((size_t)(b*NHEAD + h))*LSEQ * DHEAD;
  const u16* Vg = Vt + ((size_t)(b*NHEAD + h))*DHEAD*LSEQ;
#pragma unroll
  for (int i = 0; i < 4; i++) {
    int row = wave*16 + i*4;
    ASYNC16(Qg + (size_t)(row + fq)*DHEAD + fm*8, &Qs[row*DHEAD]);
  }
  const f32x4 fzero = {0.f, 0.f, 0.f, 0.f};
  f32x4 o[8];
#pragma unroll
  for (int i = 0; i < 8; i++) o[i] = fzero;
  float m_i[4], l_i[4];
#pragma unroll
  for (int r = 0; r < 4; r++) { m_i[r] = -1e30f; l_i[r] = 0.f; }
  for (int kt = 0; kt < 32; kt++) {
    const u16* Kt_ = Kg + (size_t)kt*64*DHEAD;
    const u16* Vt_ = Vg + kt*64;
#pragma unroll
    for (int i = 0; i < 4; i++) {
      int row = wave*16 + i*4;
      ASYNC16(Kt_ + (size_t)(row + fq)*DHEAD + fm*8, &Ks[row*DHEAD]);
      int vrow = wave*32 + i*8;
      ASYNC16(Vt_ + (size_t)(vrow + r8)*LSEQ + c8*8, &Vs[vrow*64]);
    }
    __syncthreads();
    f32x4 s[4];
#pragma unroll
    for (int nt = 0; nt < 4; nt++) s[nt] = fzero;
#pragma unroll
    for (int ks = 0; ks < 4; ks++) {
      short8 aq = *(const short8*)&Qs[(wave*16 + fm)*DHEAD + ks*32 + fq*8];
#pragma unroll
      for (int nt = 0; nt < 4; nt++) {
        short8 bk = *(const short8*)&Ks[(nt*16 + fm)*DHEAD + ks*32 + fq*8];
        s[nt] = __builtin_amdgcn_mfma_f32_16x16x32_bf16(aq, bk, s[nt], 0, 0, 0);
      }
    }
    float rowm[4];
#pragma unroll
    for (int r = 0; r < 4; r++)
      rowm[r] = fmaxf(fmaxf(s[0][r], s[1][r]), fmaxf(s[2][r], s[3][r])) * ATT_SCALE;
#pragma unroll
    for (int r = 0; r < 4; r++) {
#pragma unroll
      for (int o2 = 8; o2 >= 1; o2 >>= 1)
        rowm[r] = fmaxf(rowm[r], __shfl_xor(rowm[r], o2, 64));
    }
    float alpha[4];
#pragma unroll
    for (int r = 0; r < 4; r++) {
      float mnew = fmaxf(m_i[r], rowm[r]);
      alpha[r] = __expf(m_i[r] - mnew);
      m_i[r] = mnew;
    }
    float rs[4] = {0.f, 0.f, 0.f, 0.f};
#pragma unroll
    for (int nt = 0; nt < 4; nt++)
#pragma unroll
      for (int r = 0; r < 4; r++) {
        float p = __expf(s[nt][r] * ATT_SCALE - m_i[r]);
        s[nt][r] = p;
        rs[r] += p;
      }
#pragma unroll
    for (int r = 0; r < 4; r++) {
#pragma unroll
      for (int o2 = 8; o2 >= 1; o2 >>= 1) rs[r] += __shfl_xor(rs[r], o2, 64);
      l_i[r] = l_i[r] * alpha[r] + rs[r];
    }
#pragma unroll
    for (int i = 0; i < 8; i++)
#pragma unroll
      for (int r = 0; r < 4; r++) o[i][r] *= alpha[r];
#pragma unroll
    for (int nt = 0; nt < 4; nt++)
#pragma unroll
      for (int r = 0; r < 4; r++)
        Ps[(wave*16 + fq*4 + r)*72 + nt*16 + fm] = f2bf(s[nt][r]);
    __syncthreads();
#pragma unroll
    for (int ks = 0; ks < 2; ks++) {
      short8 ap = *(const short8*)&Ps[(wave*16 + fm)*72 + ks*32 + fq*8];
#pragma unroll
      for (int nt = 0; nt < 8; nt++) {
        short8 bv = *(const short8*)&Vs[(nt*16 + fm)*64 + ks*32 + fq*8];
        o[nt] = __builtin_amdgcn_mfma_f32_16x16x32_bf16(ap, bv, o[nt], 0, 0, 0);
      }
    }
    __syncthreads();
  }
#pragma unroll
  for (int nt = 0; nt < 8; nt++) {
#pragma unroll
    for (int r = 0; r < 4; r++) {
      int l = qt*64 + wave*16 + fq*4 + r;
      int d = nt*16 + fm;
      float v = o[nt][r] / l_i[r];
      cat[((size_t)(b*LSEQ + l))*NC + h*DHEAD + d] = f2bf(v);
    }
  }
}

// ---------------- launch ----------------
extern "C" void kernel_launch(void* const* d_in, const int* in_sizes, int n_in,
                              void* d_out, int out_size, void* d_ws, size_t ws_size,
                              hipStream_t stream) {
  const float* x       = (const float*)d_in[0];
  const float* vec     = (const float*)d_in[1];
  const float* pe      = (const float*)d_in[2];
  const float* mod_w   = (const float*)d_in[3];
  const float* mod_b   = (const float*)d_in[4];
  const float* lin1_w  = (const float*)d_in[5];
  const float* lin1_b  = (const float*)d_in[6];
  const float* lin2_w  = (const float*)d_in[7];
  const float* lin2_b  = (const float*)d_in[8];
  const float* q_scale = (const float*)d_in[9];
  const float* k_scale = (const float*)d_in[10];
  char* ws = (char*)d_ws;

  // workspace layout (requires ~252 MB)
  float* modv = (float*)(ws + 0);                 //  48 KB
  u16* xmod  = (u16*)(ws + 65536ULL);             //  16.8 MB
  u16* qkv   = (u16*)(ws + 16842752ULL);          //  50.3 MB
  u16* cat   = (u16*)(ws + 67174400ULL);          //  83.9 MB
  u16* w2    = (u16*)(ws + 151060480ULL);         //  41.9 MB
  u16* w1    = (u16*)(ws + 193003520ULL);         //  58.7 MB (dead after GEMM1)
  u16* Qb    = (u16*)(ws + 193003520ULL);         //  aliases w1
  u16* Kb    = (u16*)(ws + 209780736ULL);
  u16* Vtb   = (u16*)(ws + 226557952ULL);

  k_mod<<<dim3(3*HDIM), dim3(256), 0, stream>>>(vec, mod_w, mod_b, modv);
  k_cvt<<<dim3(4096), dim3(256), 0, stream>>>((const float4*)lin1_w, (ushort4*)w1, (N1*HDIM)/4);
  k_cvt<<<dim3(4096), dim3(256), 0, stream>>>((const float4*)lin2_w, (ushort4*)w2, (HDIM*NC)/4);
  k_ln<<<dim3(4096), dim3(256), 0, stream>>>(x, modv, xmod);
  k_gemm1<<<dim3(32*112), dim3(256), 0, stream>>>(xmod, w1, lin1_b, qkv, cat);
  k_qk<<<dim3(65536), dim3(128), 0, stream>>>(qkv, pe, q_scale, k_scale, Qb, Kb);
  k_vt<<<dim3(1024), dim3(256), 0, stream>>>(qkv, Vtb);
  k_attn<<<dim3(1024), dim3(256), 0, stream>>>(Qb, Kb, Vtb, cat);
  k_gemm2<<<dim3(32*16), dim3(256), 0, stream>>>(cat, w2, lin2_b, x, modv, (float*)d_out);
}

// Round 2
// 1184.873 us; speedup vs baseline: 1.0235x; 1.0235x over previous
//
#include <hip/hip_runtime.h>

#define LSEQ 2048
#define HDIM 2048
#define NHEAD 16
#define DHEAD 128
#define N1 14336   // 3H + MLP
#define NC 10240   // H + MLP

typedef unsigned short u16;
typedef __attribute__((ext_vector_type(8))) short short8;
typedef __attribute__((ext_vector_type(4))) float f32x4;

#define ASYNC16(g, l) __builtin_amdgcn_global_load_lds( \
    (__attribute__((address_space(1))) void*)(g),        \
    (__attribute__((address_space(3))) void*)(l), 16, 0, 0)

__device__ __forceinline__ u16 f2bf(float f) {
  unsigned u = __builtin_bit_cast(unsigned, f);
  u += 0x7fffu + ((u >> 16) & 1u);
  return (u16)(u >> 16);
}
__device__ __forceinline__ float bf2f(u16 v) {
  unsigned u = ((unsigned)v) << 16;
  return __builtin_bit_cast(float, u);
}
__device__ __forceinline__ float silu_f(float x) { return x / (1.f + __expf(-x)); }
__device__ __forceinline__ float gelu_f(float x) {
  float u = 0.7978845608028654f * (x + 0.044715f * x * x * x);
  float e = __expf(2.f * u);
  float th = 1.f - 2.f / (e + 1.f);
  return 0.5f * x * (1.f + th);
}

// ---------------- mod = silu(vec) @ mod_w.T + mod_b ----------------
__global__ __launch_bounds__(256) void k_mod(const float* __restrict__ vec,
                                             const float* __restrict__ mod_w,
                                             const float* __restrict__ mod_b,
                                             float* __restrict__ modv) {
  int j = blockIdx.x, t = threadIdx.x;
  const float4* wr = (const float4*)(mod_w + (size_t)j * HDIM);
  const float4* vv = (const float4*)vec;
  float s0 = 0.f, s1 = 0.f;
#pragma unroll
  for (int i = 0; i < 2; i++) {
    int idx = t + i * 256;
    float4 w = wr[idx];
    float4 a = vv[idx];
    float4 c = vv[idx + 512];
    s0 += w.x*silu_f(a.x) + w.y*silu_f(a.y) + w.z*silu_f(a.z) + w.w*silu_f(a.w);
    s1 += w.x*silu_f(c.x) + w.y*silu_f(c.y) + w.z*silu_f(c.z) + w.w*silu_f(c.w);
  }
  int lane = t & 63, wid = t >> 6;
#pragma unroll
  for (int o = 32; o; o >>= 1) { s0 += __shfl_down(s0, o, 64); s1 += __shfl_down(s1, o, 64); }
  __shared__ float red[8];
  if (!lane) { red[wid] = s0; red[4 + wid] = s1; }
  __syncthreads();
  if (!t) {
    float b_ = mod_b[j];
    modv[j] = red[0]+red[1]+red[2]+red[3] + b_;
    modv[3*HDIM + j] = red[4]+red[5]+red[6]+red[7] + b_;
  }
}

// ---------------- x_mod = (1+scale)*LN(x) + shift, bf16 ----------------
__global__ __launch_bounds__(256) void k_ln(const float* __restrict__ x,
                                            const float* __restrict__ modv,
                                            u16* __restrict__ xmod) {
  int row = blockIdx.x, t = threadIdx.x;
  int b = row >> 11;
  const float4* xr = (const float4*)(x + (size_t)row * HDIM);
  float4 v0 = xr[t], v1 = xr[t + 256];
  float sum = v0.x+v0.y+v0.z+v0.w + v1.x+v1.y+v1.z+v1.w;
  float sq  = v0.x*v0.x+v0.y*v0.y+v0.z*v0.z+v0.w*v0.w
            + v1.x*v1.x+v1.y*v1.y+v1.z*v1.z+v1.w*v1.w;
  int lane = t & 63, wid = t >> 6;
#pragma unroll
  for (int o = 32; o; o >>= 1) { sum += __shfl_down(sum, o, 64); sq += __shfl_down(sq, o, 64); }
  __shared__ float red[8];
  if (!lane) { red[wid] = sum; red[4+wid] = sq; }
  __syncthreads();
  sum = red[0]+red[1]+red[2]+red[3];
  sq  = red[4]+red[5]+red[6]+red[7];
  float mu = sum * (1.f/HDIM);
  float rstd = rsqrtf(sq * (1.f/HDIM) - mu*mu + 1e-6f);
  const float* mb = modv + b * (3*HDIM);
  u16* orow = xmod + (size_t)row * HDIM;
  float vv[8] = {v0.x,v0.y,v0.z,v0.w,v1.x,v1.y,v1.z,v1.w};
#pragma unroll
  for (int half = 0; half < 2; half++) {
    int h0 = (t + half*256) * 4;
    ushort4 o4;
    float e0 = (1.f + mb[HDIM + h0+0]) * ((vv[half*4+0]-mu)*rstd) + mb[h0+0];
    float e1 = (1.f + mb[HDIM + h0+1]) * ((vv[half*4+1]-mu)*rstd) + mb[h0+1];
    float e2 = (1.f + mb[HDIM + h0+2]) * ((vv[half*4+2]-mu)*rstd) + mb[h0+2];
    float e3 = (1.f + mb[HDIM + h0+3]) * ((vv[half*4+3]-mu)*rstd) + mb[h0+3];
    o4.x = f2bf(e0); o4.y = f2bf(e1); o4.z = f2bf(e2); o4.w = f2bf(e3);
    *(ushort4*)(orow + h0) = o4;
  }
}

// ---------------- f32 -> bf16 weight convert ----------------
__global__ __launch_bounds__(256) void k_cvt(const float4* __restrict__ src,
                                             ushort4* __restrict__ dst, int n4) {
  int i = blockIdx.x * 256 + threadIdx.x;
  int stride = gridDim.x * 256;
  for (; i < n4; i += stride) {
    float4 v = src[i];
    ushort4 o;
    o.x = f2bf(v.x); o.y = f2bf(v.y); o.z = f2bf(v.z); o.w = f2bf(v.w);
    dst[i] = o;
  }
}

// ---------------- GEMM1: h = xmod @ W1^T + b1 ; split qkv / gelu(mlp) ----------------
// Epilogue staged through LDS for coalesced ushort8 stores.
__global__ __launch_bounds__(256, 2) void k_gemm1(const u16* __restrict__ A,
                                                  const u16* __restrict__ Bw,
                                                  const float* __restrict__ bias,
                                                  u16* __restrict__ qkv,
                                                  u16* __restrict__ cat) {
  const int K = HDIM;
  const int NB = N1 / 128;  // 112
  int bid = blockIdx.x;
  int bm = bid / NB, bn = bid % NB;
  int t = threadIdx.x, wave = t >> 6, lane = t & 63;
  int wm = wave >> 1, wn = wave & 1;
  __shared__ u16 S[128 * 136];          // loop: As=S[0..4095], Bs=S[4096..8191]; epi: 128x136
  u16* As = S;
  u16* Bs = S + 4096;
  const f32x4 fzero = {0.f, 0.f, 0.f, 0.f};
  f32x4 acc[4][4];
#pragma unroll
  for (int i = 0; i < 4; i++)
#pragma unroll
    for (int j2 = 0; j2 < 4; j2++) acc[i][j2] = fzero;
  const u16* Ab = A + (size_t)bm * 128 * K;
  const u16* Bb = Bw + (size_t)bn * 128 * K;
  int r4 = lane >> 2, c4 = lane & 3;
  int fm = lane & 15, fk = (lane >> 4) * 8, fq = lane >> 4;
  for (int k0 = 0; k0 < K; k0 += 32) {
#pragma unroll
    for (int i = 0; i < 2; i++) {
      int row = wave*32 + i*16;
      ASYNC16(Ab + (size_t)(row + r4)*K + k0 + c4*8, &As[row*32]);
      ASYNC16(Bb + (size_t)(row + r4)*K + k0 + c4*8, &Bs[row*32]);
    }
    __syncthreads();
    short8 af[4], bfr[4];
#pragma unroll
    for (int mt = 0; mt < 4; mt++)
      af[mt] = *(const short8*)&As[(wm*64 + mt*16 + fm)*32 + fk];
#pragma unroll
    for (int nt = 0; nt < 4; nt++)
      bfr[nt] = *(const short8*)&Bs[(wn*64 + nt*16 + fm)*32 + fk];
#pragma unroll
    for (int mt = 0; mt < 4; mt++)
#pragma unroll
      for (int nt = 0; nt < 4; nt++)
        acc[mt][nt] = __builtin_amdgcn_mfma_f32_16x16x32_bf16(af[mt], bfr[nt], acc[mt][nt], 0, 0, 0);
    __syncthreads();
  }
  // ---- epilogue phase 1: bias (+gelu for mlp cols), write bf16 tile to LDS ----
  bool ismlp = (bn >= 48);              // 3H = 6144 = 48*128, uniform per block
#pragma unroll
  for (int nt = 0; nt < 4; nt++) {
    int col_l = wn*64 + nt*16 + fm;
    float bv = bias[bn*128 + col_l];
#pragma unroll
    for (int mt = 0; mt < 4; mt++) {
#pragma unroll
      for (int rr = 0; rr < 4; rr++) {
        int row_l = wm*64 + mt*16 + fq*4 + rr;
        float v = acc[mt][nt][rr] + bv;
        if (ismlp) v = gelu_f(v);
        S[row_l*136 + col_l] = f2bf(v);
      }
    }
  }
  __syncthreads();
  // ---- epilogue phase 2: coalesced 16B stores ----
  int c = (t & 15) * 8;
  int rq = t >> 4;                      // 0..15
#pragma unroll
  for (int p = 0; p < 8; p++) {
    int r_l = p*16 + rq;
    short8 v = *(const short8*)&S[r_l*136 + c];
    int row_g = bm*128 + r_l;
    if (!ismlp)
      *(short8*)(qkv + (size_t)row_g*(3*HDIM) + bn*128 + c) = v;
    else
      *(short8*)(cat + (size_t)row_g*NC + HDIM + (bn-48)*128 + c) = v;
  }
}

// ---------------- GEMM2: out = x + gate*(cat @ W2^T + b2) ----------------
__global__ __launch_bounds__(256, 2) void k_gemm2(const u16* __restrict__ A,
                                                  const u16* __restrict__ Bw,
                                                  const float* __restrict__ bias,
                                                  const float* __restrict__ xres,
                                                  const float* __restrict__ modv,
                                                  float* __restrict__ out) {
  const int K = NC;
  const int NB = HDIM / 128;  // 16
  int bid = blockIdx.x;
  int bm = bid / NB, bn = bid % NB;
  int t = threadIdx.x, wave = t >> 6, lane = t & 63;
  int wm = wave >> 1, wn = wave & 1;
  __shared__ u16 As[128 * 32];
  __shared__ u16 Bs[128 * 32];
  const f32x4 fzero = {0.f, 0.f, 0.f, 0.f};
  f32x4 acc[4][4];
#pragma unroll
  for (int i = 0; i < 4; i++)
#pragma unroll
    for (int j2 = 0; j2 < 4; j2++) acc[i][j2] = fzero;
  const u16* Ab = A + (size_t)bm * 128 * K;
  const u16* Bb = Bw + (size_t)bn * 128 * K;
  int r4 = lane >> 2, c4 = lane & 3;
  int fm = lane & 15, fk = (lane >> 4) * 8;
  for (int k0 = 0; k0 < K; k0 += 32) {
#pragma unroll
    for (int i = 0; i < 2; i++) {
      int row = wave*32 + i*16;
      ASYNC16(Ab + (size_t)(row + r4)*K + k0 + c4*8, &As[row*32]);
      ASYNC16(Bb + (size_t)(row + r4)*K + k0 + c4*8, &Bs[row*32]);
    }
    __syncthreads();
    short8 af[4], bfr[4];
#pragma unroll
    for (int mt = 0; mt < 4; mt++)
      af[mt] = *(const short8*)&As[(wm*64 + mt*16 + fm)*32 + fk];
#pragma unroll
    for (int nt = 0; nt < 4; nt++)
      bfr[nt] = *(const short8*)&Bs[(wn*64 + nt*16 + fm)*32 + fk];
#pragma unroll
    for (int mt = 0; mt < 4; mt++)
#pragma unroll
      for (int nt = 0; nt < 4; nt++)
        acc[mt][nt] = __builtin_amdgcn_mfma_f32_16x16x32_bf16(af[mt], bfr[nt], acc[mt][nt], 0, 0, 0);
    __syncthreads();
  }
  int rbase = bm*128 + wm*64;
  int cbase = bn*128 + wn*64;
  int b = (bm*128) >> 11;
#pragma unroll
  for (int nt = 0; nt < 4; nt++) {
    int col = cbase + nt*16 + fm;
    float bv = bias[col];
    float g = modv[b*(3*HDIM) + 2*HDIM + col];
#pragma unroll
    for (int mt = 0; mt < 4; mt++) {
#pragma unroll
      for (int rr = 0; rr < 4; rr++) {
        int row = rbase + mt*16 + (lane>>4)*4 + rr;
        size_t idx = (size_t)row*HDIM + col;
        out[idx] = xres[idx] + g * (acc[mt][nt][rr] + bv);
      }
    }
  }
}

// ---------------- q,k: rmsnorm + rope -> Q,K (b,h,l,d) bf16, fully vectorized ----------------
__global__ __launch_bounds__(256) void k_qk(const u16* __restrict__ qkv,
                                            const float* __restrict__ pe,
                                            const float* __restrict__ q_scale,
                                            const float* __restrict__ k_scale,
                                            u16* __restrict__ Q, u16* __restrict__ Ko) {
  int bid = blockIdx.x;                  // b*L + l
  int l = bid & (LSEQ-1);
  int b = bid >> 11;
  int t = threadIdx.x;
  int h = t >> 4;                        // head 0..15
  int dc = (t & 15) * 8;                 // dim-in-head base
  const u16* base = qkv + (size_t)bid * (3*HDIM);
  short8 q8 = *(const short8*)(base + h*DHEAD + dc);
  short8 k8 = *(const short8*)(base + HDIM + h*DHEAD + dc);
  float qf[8], kf[8];
  float sq = 0.f, sk = 0.f;
#pragma unroll
  for (int i = 0; i < 8; i++) {
    qf[i] = bf2f((u16)q8[i]); kf[i] = bf2f((u16)k8[i]);
    sq += qf[i]*qf[i]; sk += kf[i]*kf[i];
  }
#pragma unroll
  for (int m = 1; m < 16; m <<= 1) { sq += __shfl_xor(sq, m, 64); sk += __shfl_xor(sk, m, 64); }
  float rq = rsqrtf(sq * (1.f/DHEAD) + 1e-6f);
  float rk = rsqrtf(sk * (1.f/DHEAD) + 1e-6f);
  float4 qs0 = *(const float4*)(q_scale + dc), qs1 = *(const float4*)(q_scale + dc + 4);
  float4 ks0 = *(const float4*)(k_scale + dc), ks1 = *(const float4*)(k_scale + dc + 4);
  float qsc[8] = {qs0.x,qs0.y,qs0.z,qs0.w,qs1.x,qs1.y,qs1.z,qs1.w};
  float ksc[8] = {ks0.x,ks0.y,ks0.z,ks0.w,ks1.x,ks1.y,ks1.z,ks1.w};
  float qn[8], kn[8];
#pragma unroll
  for (int i = 0; i < 8; i++) { qn[i] = qf[i]*rq*qsc[i]; kn[i] = kf[i]*rk*ksc[i]; }
  const float4* pe4 = (const float4*)pe + ((size_t)bid*64 + (dc >> 1));
  short8 qo, ko;
#pragma unroll
  for (int pi = 0; pi < 4; pi++) {
    float4 pp = pe4[pi];
    float q0 = pp.x*qn[2*pi] + pp.y*qn[2*pi+1];
    float q1 = pp.z*qn[2*pi] + pp.w*qn[2*pi+1];
    float k0 = pp.x*kn[2*pi] + pp.y*kn[2*pi+1];
    float k1 = pp.z*kn[2*pi] + pp.w*kn[2*pi+1];
    qo[2*pi] = (short)f2bf(q0); qo[2*pi+1] = (short)f2bf(q1);
    ko[2*pi] = (short)f2bf(k0); ko[2*pi+1] = (short)f2bf(k1);
  }
  size_t oidx = (((size_t)(b*NHEAD + h))*LSEQ + l)*DHEAD + dc;
  *(short8*)(Q + oidx) = qo;
  *(short8*)(Ko + oidx) = ko;
}

// ---------------- V transpose: qkv v-part -> Vt (b,h,d,l) bf16 ----------------
__global__ __launch_bounds__(256) void k_vt(const u16* __restrict__ qkv, u16* __restrict__ Vt) {
  int bid = blockIdx.x;
  int lt = bid & 31, h = (bid >> 5) & 15, b = bid >> 9;
  __shared__ u16 tile[64][132];
  int t = threadIdx.x;
#pragma unroll
  for (int it = 0; it < 8; it++) {
    int idx = it*1024 + t*4;
    int li = idx >> 7, di = idx & 127;
    const u16* src = qkv + ((size_t)(b*LSEQ + lt*64 + li))*(3*HDIM) + 2*HDIM + h*DHEAD + di;
    ushort4 v = *(const ushort4*)src;
    *(ushort4*)&tile[li][di] = v;
  }
  __syncthreads();
  u16* dst = Vt + ((size_t)(b*NHEAD + h))*DHEAD*LSEQ + lt*64;
#pragma unroll
  for (int it = 0; it < 32; it++) {
    int idx = it*256 + t;
    int lo = idx & 63, dd = idx >> 6;
    dst[(size_t)dd*LSEQ + lo] = tile[lo][dd];
  }
}

// ---------------- flash attention: 1 barrier/iter, dbuf K/V, Q in regs ----------------
#define ATT_SCALE 0.08838834764831845f
__global__ __launch_bounds__(256, 2) void k_attn(const u16* __restrict__ Q,
                                                 const u16* __restrict__ Kc,
                                                 const u16* __restrict__ Vt,
                                                 u16* __restrict__ cat) {
  __shared__ u16 Ks[2*64*128];   // 32 KB
  __shared__ u16 Vs[2*128*64];   // 32 KB
  __shared__ u16 Ps[64*88];      // 11 KB, per-wave private rows
  int bid = blockIdx.x;
  int bh = bid & 31, qt = bid >> 5;       // bh fast => XCD gets 4 heads' K/V (L2 fit)
  int h = bh & 15, b = bh >> 4;
  int t = threadIdx.x, wave = t >> 6, lane = t & 63;
  int fm = lane & 15, fq = lane >> 4;
  int r8 = lane >> 3, c8 = lane & 7;
  const u16* Qg = Q  + (((size_t)(b*NHEAD + h))*LSEQ + qt*64) * DHEAD;
  const u16* Kg = Kc + ((size_t)(b*NHEAD + h))*LSEQ * DHEAD;
  const u16* Vg = Vt + ((size_t)(b*NHEAD + h))*DHEAD*LSEQ;
  // Q fragments directly to registers
  short8 aq[4];
#pragma unroll
  for (int ks = 0; ks < 4; ks++)
    aq[ks] = *(const short8*)(Qg + (size_t)(wave*16 + fm)*DHEAD + ks*32 + fq*8);
  // prologue: stage tile 0 into buffer 0
#pragma unroll
  for (int i = 0; i < 4; i++) {
    int row = wave*16 + i*4;
    ASYNC16(Kg + (size_t)(row + fq)*DHEAD + fm*8, &Ks[row*DHEAD]);
    int vrow = wave*32 + i*8;
    ASYNC16(Vg + (size_t)(vrow + r8)*LSEQ + c8*8, &Vs[vrow*64]);
  }
  const f32x4 fzero = {0.f, 0.f, 0.f, 0.f};
  f32x4 o[8];
#pragma unroll
  for (int i = 0; i < 8; i++) o[i] = fzero;
  float m_i[4], l_i[4];
#pragma unroll
  for (int r = 0; r < 4; r++) { m_i[r] = -1e30f; l_i[r] = 0.f; }
  for (int kt = 0; kt < 32; kt++) {
    int cur = kt & 1;
    __syncthreads();   // drains prev-iter staging (issued a full iter ago); protects buf reuse
    if (kt < 31) {
      int off = (cur ^ 1) * 8192;
      const u16* Kt_ = Kg + (size_t)(kt+1)*64*DHEAD;
      const u16* Vt_ = Vg + (kt+1)*64;
#pragma unroll
      for (int i = 0; i < 4; i++) {
        int row = wave*16 + i*4;
        ASYNC16(Kt_ + (size_t)(row + fq)*DHEAD + fm*8, &Ks[off + row*DHEAD]);
        int vrow = wave*32 + i*8;
        ASYNC16(Vt_ + (size_t)(vrow + r8)*LSEQ + c8*8, &Vs[off + vrow*64]);
      }
    }
    const u16* Kb = &Ks[cur*8192];
    const u16* Vb = &Vs[cur*8192];
    f32x4 s[4];
#pragma unroll
    for (int nt = 0; nt < 4; nt++) s[nt] = fzero;
#pragma unroll
    for (int ks = 0; ks < 4; ks++) {
#pragma unroll
      for (int nt = 0; nt < 4; nt++) {
        short8 bk = *(const short8*)&Kb[(nt*16 + fm)*DHEAD + ks*32 + fq*8];
        s[nt] = __builtin_amdgcn_mfma_f32_16x16x32_bf16(aq[ks], bk, s[nt], 0, 0, 0);
      }
    }
    float rowm[4];
#pragma unroll
    for (int r = 0; r < 4; r++)
      rowm[r] = fmaxf(fmaxf(s[0][r], s[1][r]), fmaxf(s[2][r], s[3][r])) * ATT_SCALE;
#pragma unroll
    for (int r = 0; r < 4; r++) {
#pragma unroll
      for (int o2 = 8; o2 >= 1; o2 >>= 1)
        rowm[r] = fmaxf(rowm[r], __shfl_xor(rowm[r], o2, 64));
    }
    float alpha[4];
#pragma unroll
    for (int r = 0; r < 4; r++) {
      float mnew = fmaxf(m_i[r], rowm[r]);
      alpha[r] = __expf(m_i[r] - mnew);
      m_i[r] = mnew;
    }
    float rs[4] = {0.f, 0.f, 0.f, 0.f};
#pragma unroll
    for (int nt = 0; nt < 4; nt++)
#pragma unroll
      for (int r = 0; r < 4; r++) {
        float p = __expf(s[nt][r] * ATT_SCALE - m_i[r]);
        s[nt][r] = p;
        rs[r] += p;
      }
#pragma unroll
    for (int r = 0; r < 4; r++) {
#pragma unroll
      for (int o2 = 8; o2 >= 1; o2 >>= 1) rs[r] += __shfl_xor(rs[r], o2, 64);
      l_i[r] = l_i[r] * alpha[r] + rs[r];
    }
#pragma unroll
    for (int i = 0; i < 8; i++)
#pragma unroll
      for (int r = 0; r < 4; r++) o[i][r] *= alpha[r];
    // P tile: per-wave private rows -> no __syncthreads needed, just lgkm drain
#pragma unroll
    for (int nt = 0; nt < 4; nt++)
#pragma unroll
      for (int r = 0; r < 4; r++)
        Ps[(wave*16 + fq*4 + r)*88 + nt*16 + fm] = f2bf(s[nt][r]);
    asm volatile("s_waitcnt lgkmcnt(0)" ::: "memory");
#pragma unroll
    for (int ks2 = 0; ks2 < 2; ks2++) {
      short8 ap = *(const short8*)&Ps[(wave*16 + fm)*88 + ks2*32 + fq*8];
#pragma unroll
      for (int nt = 0; nt < 8; nt++) {
        short8 bv = *(const short8*)&Vb[(nt*16 + fm)*64 + ks2*32 + fq*8];
        o[nt] = __builtin_amdgcn_mfma_f32_16x16x32_bf16(ap, bv, o[nt], 0, 0, 0);
      }
    }
  }
#pragma unroll
  for (int nt = 0; nt < 8; nt++) {
#pragma unroll
    for (int r = 0; r < 4; r++) {
      int l = qt*64 + wave*16 + fq*4 + r;
      int d = nt*16 + fm;
      float v = o[nt][r] / l_i[r];
      cat[((size_t)(b*LSEQ + l))*NC + h*DHEAD + d] = f2bf(v);
    }
  }
}

// ---------------- launch ----------------
extern "C" void kernel_launch(void* const* d_in, const int* in_sizes, int n_in,
                              void* d_out, int out_size, void* d_ws, size_t ws_size,
                              hipStream_t stream) {
  const float* x       = (const float*)d_in[0];
  const float* vec     = (const float*)d_in[1];
  const float* pe      = (const float*)d_in[2];
  const float* mod_w   = (const float*)d_in[3];
  const float* mod_b   = (const float*)d_in[4];
  const float* lin1_w  = (const float*)d_in[5];
  const float* lin1_b  = (const float*)d_in[6];
  const float* lin2_w  = (const float*)d_in[7];
  const float* lin2_b  = (const float*)d_in[8];
  const float* q_scale = (const float*)d_in[9];
  const float* k_scale = (const float*)d_in[10];
  char* ws = (char*)d_ws;

  float* modv = (float*)(ws + 0);                 //  48 KB
  u16* xmod  = (u16*)(ws + 65536ULL);             //  16.8 MB
  u16* qkv   = (u16*)(ws + 16842752ULL);          //  50.3 MB
  u16* cat   = (u16*)(ws + 67174400ULL);          //  83.9 MB
  u16* w2    = (u16*)(ws + 151060480ULL);         //  41.9 MB
  u16* w1    = (u16*)(ws + 193003520ULL);         //  58.7 MB (dead after GEMM1)
  u16* Qb    = (u16*)(ws + 193003520ULL);         //  aliases w1
  u16* Kb    = (u16*)(ws + 209780736ULL);
  u16* Vtb   = (u16*)(ws + 226557952ULL);

  k_mod<<<dim3(3*HDIM), dim3(256), 0, stream>>>(vec, mod_w, mod_b, modv);
  k_cvt<<<dim3(4096), dim3(256), 0, stream>>>((const float4*)lin1_w, (ushort4*)w1, (N1*HDIM)/4);
  k_cvt<<<dim3(4096), dim3(256), 0, stream>>>((const float4*)lin2_w, (ushort4*)w2, (HDIM*NC)/4);
  k_ln<<<dim3(4096), dim3(256), 0, stream>>>(x, modv, xmod);
  k_gemm1<<<dim3(32*112), dim3(256), 0, stream>>>(xmod, w1, lin1_b, qkv, cat);
  k_qk<<<dim3(4096), dim3(256), 0, stream>>>(qkv, pe, q_scale, k_scale, Qb, Kb);
  k_vt<<<dim3(1024), dim3(256), 0, stream>>>(qkv, Vtb);
  k_attn<<<dim3(1024), dim3(256), 0, stream>>>(Qb, Kb, Vtb, cat);
  k_gemm2<<<dim3(32*16), dim3(256), 0, stream>>>(cat, w2, lin2_b, x, modv, (float*)d_out);
}

// Round 3
// 1011.638 us; speedup vs baseline: 1.1988x; 1.1712x over previous
//
#include <hip/hip_runtime.h>

#define LSEQ 2048
#define HDIM 2048
#define NHEAD 16
#define DHEAD 128
#define N1 14336   // 3H + MLP
#define NC 10240   // H + MLP

typedef unsigned short u16;
typedef __attribute__((ext_vector_type(8))) short short8;
typedef __attribute__((ext_vector_type(4))) float f32x4;

#define ASYNC16(g, l) __builtin_amdgcn_global_load_lds( \
    (__attribute__((address_space(1))) void*)(g),        \
    (__attribute__((address_space(3))) void*)(l), 16, 0, 0)

__device__ __forceinline__ u16 f2bf(float f) {
  unsigned u = __builtin_bit_cast(unsigned, f);
  u += 0x7fffu + ((u >> 16) & 1u);
  return (u16)(u >> 16);
}
__device__ __forceinline__ u16 f2bf_trunc(float f) {   // for probs in [0,1]
  return (u16)(__builtin_bit_cast(unsigned, f) >> 16);
}
__device__ __forceinline__ float bf2f(u16 v) {
  unsigned u = ((unsigned)v) << 16;
  return __builtin_bit_cast(float, u);
}
__device__ __forceinline__ float silu_f(float x) { return x / (1.f + __expf(-x)); }
__device__ __forceinline__ float gelu_f(float x) {
  float u = 0.7978845608028654f * (x + 0.044715f * x * x * x);
  float e = __expf(2.f * u);
  float th = 1.f - 2.f / (e + 1.f);
  return 0.5f * x * (1.f + th);
}

// ---------------- mod = silu(vec) @ mod_w.T + mod_b ----------------
__global__ __launch_bounds__(256) void k_mod(const float* __restrict__ vec,
                                             const float* __restrict__ mod_w,
                                             const float* __restrict__ mod_b,
                                             float* __restrict__ modv) {
  int j = blockIdx.x, t = threadIdx.x;
  const float4* wr = (const float4*)(mod_w + (size_t)j * HDIM);
  const float4* vv = (const float4*)vec;
  float s0 = 0.f, s1 = 0.f;
#pragma unroll
  for (int i = 0; i < 2; i++) {
    int idx = t + i * 256;
    float4 w = wr[idx];
    float4 a = vv[idx];
    float4 c = vv[idx + 512];
    s0 += w.x*silu_f(a.x) + w.y*silu_f(a.y) + w.z*silu_f(a.z) + w.w*silu_f(a.w);
    s1 += w.x*silu_f(c.x) + w.y*silu_f(c.y) + w.z*silu_f(c.z) + w.w*silu_f(c.w);
  }
  int lane = t & 63, wid = t >> 6;
#pragma unroll
  for (int o = 32; o; o >>= 1) { s0 += __shfl_down(s0, o, 64); s1 += __shfl_down(s1, o, 64); }
  __shared__ float red[8];
  if (!lane) { red[wid] = s0; red[4 + wid] = s1; }
  __syncthreads();
  if (!t) {
    float b_ = mod_b[j];
    modv[j] = red[0]+red[1]+red[2]+red[3] + b_;
    modv[3*HDIM + j] = red[4]+red[5]+red[6]+red[7] + b_;
  }
}

// ---------------- x_mod = (1+scale)*LN(x) + shift, bf16 ----------------
__global__ __launch_bounds__(256) void k_ln(const float* __restrict__ x,
                                            const float* __restrict__ modv,
                                            u16* __restrict__ xmod) {
  int row = blockIdx.x, t = threadIdx.x;
  int b = row >> 11;
  const float4* xr = (const float4*)(x + (size_t)row * HDIM);
  float4 v0 = xr[t], v1 = xr[t + 256];
  float sum = v0.x+v0.y+v0.z+v0.w + v1.x+v1.y+v1.z+v1.w;
  float sq  = v0.x*v0.x+v0.y*v0.y+v0.z*v0.z+v0.w*v0.w
            + v1.x*v1.x+v1.y*v1.y+v1.z*v1.z+v1.w*v1.w;
  int lane = t & 63, wid = t >> 6;
#pragma unroll
  for (int o = 32; o; o >>= 1) { sum += __shfl_down(sum, o, 64); sq += __shfl_down(sq, o, 64); }
  __shared__ float red[8];
  if (!lane) { red[wid] = sum; red[4+wid] = sq; }
  __syncthreads();
  sum = red[0]+red[1]+red[2]+red[3];
  sq  = red[4]+red[5]+red[6]+red[7];
  float mu = sum * (1.f/HDIM);
  float rstd = rsqrtf(sq * (1.f/HDIM) - mu*mu + 1e-6f);
  const float* mb = modv + b * (3*HDIM);
  u16* orow = xmod + (size_t)row * HDIM;
  float vv[8] = {v0.x,v0.y,v0.z,v0.w,v1.x,v1.y,v1.z,v1.w};
#pragma unroll
  for (int half = 0; half < 2; half++) {
    int h0 = (t + half*256) * 4;
    ushort4 o4;
    float e0 = (1.f + mb[HDIM + h0+0]) * ((vv[half*4+0]-mu)*rstd) + mb[h0+0];
    float e1 = (1.f + mb[HDIM + h0+1]) * ((vv[half*4+1]-mu)*rstd) + mb[h0+1];
    float e2 = (1.f + mb[HDIM + h0+2]) * ((vv[half*4+2]-mu)*rstd) + mb[h0+2];
    float e3 = (1.f + mb[HDIM + h0+3]) * ((vv[half*4+3]-mu)*rstd) + mb[h0+3];
    o4.x = f2bf(e0); o4.y = f2bf(e1); o4.z = f2bf(e2); o4.w = f2bf(e3);
    *(ushort4*)(orow + h0) = o4;
  }
}

// ---------------- f32 -> bf16 weight convert ----------------
__global__ __launch_bounds__(256) void k_cvt(const float4* __restrict__ src,
                                             ushort4* __restrict__ dst, int n4) {
  int i = blockIdx.x * 256 + threadIdx.x;
  int stride = gridDim.x * 256;
  for (; i < n4; i += stride) {
    float4 v = src[i];
    ushort4 o;
    o.x = f2bf(v.x); o.y = f2bf(v.y); o.z = f2bf(v.z); o.w = f2bf(v.w);
    dst[i] = o;
  }
}

// ---------------- GEMM1: h = xmod @ W1^T + b1 ; split qkv / gelu(mlp) ----------------
// BK=64 as two 32-wide panels (keeps ASYNC16 mapping + BK=32 bank pattern),
// bm-fastest block order for B-stripe reuse, LDS-staged coalesced epilogue.
__global__ __launch_bounds__(256, 2) void k_gemm1(const u16* __restrict__ A,
                                                  const u16* __restrict__ Bw,
                                                  const float* __restrict__ bias,
                                                  u16* __restrict__ qkv,
                                                  u16* __restrict__ cat) {
  const int K = HDIM;
  int bid = blockIdx.x;
  int bm = bid & 31, bn = bid >> 5;     // bm fastest: 32 consecutive blocks share B-stripe
  int t = threadIdx.x, wave = t >> 6, lane = t & 63;
  int wm = wave >> 1, wn = wave & 1;
  __shared__ u16 S[128 * 136];          // 34.8 KB; loop uses first 32 KB as 4 panels
  u16* As0 = S;
  u16* As1 = S + 4096;
  u16* Bs0 = S + 8192;
  u16* Bs1 = S + 12288;
  const f32x4 fzero = {0.f, 0.f, 0.f, 0.f};
  f32x4 acc[4][4];
#pragma unroll
  for (int i = 0; i < 4; i++)
#pragma unroll
    for (int j2 = 0; j2 < 4; j2++) acc[i][j2] = fzero;
  const u16* Ab = A + (size_t)bm * 128 * K;
  const u16* Bb = Bw + (size_t)bn * 128 * K;
  int r4 = lane >> 2, c4 = lane & 3;
  int fm = lane & 15, fk = (lane >> 4) * 8, fq = lane >> 4;
  for (int k0 = 0; k0 < K; k0 += 64) {
#pragma unroll
    for (int i = 0; i < 2; i++) {
      int row = wave*32 + i*16;
      const u16* ar = Ab + (size_t)(row + r4)*K + k0 + c4*8;
      const u16* br = Bb + (size_t)(row + r4)*K + k0 + c4*8;
      ASYNC16(ar,      &As0[row*32]);
      ASYNC16(ar + 32, &As1[row*32]);
      ASYNC16(br,      &Bs0[row*32]);
      ASYNC16(br + 32, &Bs1[row*32]);
    }
    __syncthreads();
#pragma unroll
    for (int p = 0; p < 2; p++) {
      const u16* Ap = p ? As1 : As0;
      const u16* Bp = p ? Bs1 : Bs0;
      short8 af[4], bfr[4];
#pragma unroll
      for (int mt = 0; mt < 4; mt++)
        af[mt] = *(const short8*)&Ap[(wm*64 + mt*16 + fm)*32 + fk];
#pragma unroll
      for (int nt = 0; nt < 4; nt++)
        bfr[nt] = *(const short8*)&Bp[(wn*64 + nt*16 + fm)*32 + fk];
#pragma unroll
      for (int mt = 0; mt < 4; mt++)
#pragma unroll
        for (int nt = 0; nt < 4; nt++)
          acc[mt][nt] = __builtin_amdgcn_mfma_f32_16x16x32_bf16(af[mt], bfr[nt], acc[mt][nt], 0, 0, 0);
    }
    __syncthreads();
  }
  // ---- epilogue phase 1: bias (+gelu for mlp cols), write bf16 tile to LDS ----
  bool ismlp = (bn >= 48);              // 3H = 6144 = 48*128, uniform per block
#pragma unroll
  for (int nt = 0; nt < 4; nt++) {
    int col_l = wn*64 + nt*16 + fm;
    float bv = bias[bn*128 + col_l];
#pragma unroll
    for (int mt = 0; mt < 4; mt++) {
#pragma unroll
      for (int rr = 0; rr < 4; rr++) {
        int row_l = wm*64 + mt*16 + fq*4 + rr;
        float v = acc[mt][nt][rr] + bv;
        if (ismlp) v = gelu_f(v);
        S[row_l*136 + col_l] = f2bf(v);
      }
    }
  }
  __syncthreads();
  // ---- epilogue phase 2: coalesced 16B stores ----
  int c = (t & 15) * 8;
  int rq = t >> 4;
#pragma unroll
  for (int p = 0; p < 8; p++) {
    int r_l = p*16 + rq;
    short8 v = *(const short8*)&S[r_l*136 + c];
    int row_g = bm*128 + r_l;
    if (!ismlp)
      *(short8*)(qkv + (size_t)row_g*(3*HDIM) + bn*128 + c) = v;
    else
      *(short8*)(cat + (size_t)row_g*NC + HDIM + (bn-48)*128 + c) = v;
  }
}

// ---------------- GEMM2: out = x + gate*(cat @ W2^T + b2) ----------------
__global__ __launch_bounds__(256, 2) void k_gemm2(const u16* __restrict__ A,
                                                  const u16* __restrict__ Bw,
                                                  const float* __restrict__ bias,
                                                  const float* __restrict__ xres,
                                                  const float* __restrict__ modv,
                                                  float* __restrict__ out) {
  const int K = NC;
  int bid = blockIdx.x;
  int bm = bid & 31, bn = bid >> 5;     // bm fastest
  int t = threadIdx.x, wave = t >> 6, lane = t & 63;
  int wm = wave >> 1, wn = wave & 1;
  __shared__ u16 As[2*128*32];
  __shared__ u16 Bs[2*128*32];
  const f32x4 fzero = {0.f, 0.f, 0.f, 0.f};
  f32x4 acc[4][4];
#pragma unroll
  for (int i = 0; i < 4; i++)
#pragma unroll
    for (int j2 = 0; j2 < 4; j2++) acc[i][j2] = fzero;
  const u16* Ab = A + (size_t)bm * 128 * K;
  const u16* Bb = Bw + (size_t)bn * 128 * K;
  int r4 = lane >> 2, c4 = lane & 3;
  int fm = lane & 15, fk = (lane >> 4) * 8;
  for (int k0 = 0; k0 < K; k0 += 64) {
#pragma unroll
    for (int i = 0; i < 2; i++) {
      int row = wave*32 + i*16;
      const u16* ar = Ab + (size_t)(row + r4)*K + k0 + c4*8;
      const u16* br = Bb + (size_t)(row + r4)*K + k0 + c4*8;
      ASYNC16(ar,      &As[row*32]);
      ASYNC16(ar + 32, &As[4096 + row*32]);
      ASYNC16(br,      &Bs[row*32]);
      ASYNC16(br + 32, &Bs[4096 + row*32]);
    }
    __syncthreads();
#pragma unroll
    for (int p = 0; p < 2; p++) {
      const u16* Ap = &As[p*4096];
      const u16* Bp = &Bs[p*4096];
      short8 af[4], bfr[4];
#pragma unroll
      for (int mt = 0; mt < 4; mt++)
        af[mt] = *(const short8*)&Ap[(wm*64 + mt*16 + fm)*32 + fk];
#pragma unroll
      for (int nt = 0; nt < 4; nt++)
        bfr[nt] = *(const short8*)&Bp[(wn*64 + nt*16 + fm)*32 + fk];
#pragma unroll
      for (int mt = 0; mt < 4; mt++)
#pragma unroll
        for (int nt = 0; nt < 4; nt++)
          acc[mt][nt] = __builtin_amdgcn_mfma_f32_16x16x32_bf16(af[mt], bfr[nt], acc[mt][nt], 0, 0, 0);
    }
    __syncthreads();
  }
  int rbase = bm*128 + wm*64;
  int cbase = bn*128 + wn*64;
  int b = (bm*128) >> 11;
#pragma unroll
  for (int nt = 0; nt < 4; nt++) {
    int col = cbase + nt*16 + fm;
    float bv = bias[col];
    float g = modv[b*(3*HDIM) + 2*HDIM + col];
#pragma unroll
    for (int mt = 0; mt < 4; mt++) {
#pragma unroll
      for (int rr = 0; rr < 4; rr++) {
        int row = rbase + mt*16 + (lane>>4)*4 + rr;
        size_t idx = (size_t)row*HDIM + col;
        out[idx] = xres[idx] + g * (acc[mt][nt][rr] + bv);
      }
    }
  }
}

// ---------------- q,k: rmsnorm + rope -> Q,K (b,h,l,d) bf16 ----------------
__global__ __launch_bounds__(256) void k_qk(const u16* __restrict__ qkv,
                                            const float* __restrict__ pe,
                                            const float* __restrict__ q_scale,
                                            const float* __restrict__ k_scale,
                                            u16* __restrict__ Q, u16* __restrict__ Ko) {
  int bid = blockIdx.x;                  // b*L + l
  int l = bid & (LSEQ-1);
  int b = bid >> 11;
  int t = threadIdx.x;
  int h = t >> 4;
  int dc = (t & 15) * 8;
  const u16* base = qkv + (size_t)bid * (3*HDIM);
  short8 q8 = *(const short8*)(base + h*DHEAD + dc);
  short8 k8 = *(const short8*)(base + HDIM + h*DHEAD + dc);
  float qf[8], kf[8];
  float sq = 0.f, sk = 0.f;
#pragma unroll
  for (int i = 0; i < 8; i++) {
    qf[i] = bf2f((u16)q8[i]); kf[i] = bf2f((u16)k8[i]);
    sq += qf[i]*qf[i]; sk += kf[i]*kf[i];
  }
#pragma unroll
  for (int m = 1; m < 16; m <<= 1) { sq += __shfl_xor(sq, m, 64); sk += __shfl_xor(sk, m, 64); }
  float rq = rsqrtf(sq * (1.f/DHEAD) + 1e-6f);
  float rk = rsqrtf(sk * (1.f/DHEAD) + 1e-6f);
  float4 qs0 = *(const float4*)(q_scale + dc), qs1 = *(const float4*)(q_scale + dc + 4);
  float4 ks0 = *(const float4*)(k_scale + dc), ks1 = *(const float4*)(k_scale + dc + 4);
  float qsc[8] = {qs0.x,qs0.y,qs0.z,qs0.w,qs1.x,qs1.y,qs1.z,qs1.w};
  float ksc[8] = {ks0.x,ks0.y,ks0.z,ks0.w,ks1.x,ks1.y,ks1.z,ks1.w};
  float qn[8], kn[8];
#pragma unroll
  for (int i = 0; i < 8; i++) { qn[i] = qf[i]*rq*qsc[i]; kn[i] = kf[i]*rk*ksc[i]; }
  const float4* pe4 = (const float4*)pe + ((size_t)bid*64 + (dc >> 1));
  short8 qo, ko;
#pragma unroll
  for (int pi = 0; pi < 4; pi++) {
    float4 pp = pe4[pi];
    float q0 = pp.x*qn[2*pi] + pp.y*qn[2*pi+1];
    float q1 = pp.z*qn[2*pi] + pp.w*qn[2*pi+1];
    float k0 = pp.x*kn[2*pi] + pp.y*kn[2*pi+1];
    float k1 = pp.z*kn[2*pi] + pp.w*kn[2*pi+1];
    qo[2*pi] = (short)f2bf(q0); qo[2*pi+1] = (short)f2bf(q1);
    ko[2*pi] = (short)f2bf(k0); ko[2*pi+1] = (short)f2bf(k1);
  }
  size_t oidx = (((size_t)(b*NHEAD + h))*LSEQ + l)*DHEAD + dc;
  *(short8*)(Q + oidx) = qo;
  *(short8*)(Ko + oidx) = ko;
}

// ---------------- V transpose: qkv v-part -> Vt (b,h,d,l) bf16 ----------------
__global__ __launch_bounds__(256) void k_vt(const u16* __restrict__ qkv, u16* __restrict__ Vt) {
  int bid = blockIdx.x;
  int lt = bid & 31, h = (bid >> 5) & 15, b = bid >> 9;
  __shared__ u16 tile[64][132];
  int t = threadIdx.x;
#pragma unroll
  for (int it = 0; it < 8; it++) {
    int idx = it*1024 + t*4;
    int li = idx >> 7, di = idx & 127;
    const u16* src = qkv + ((size_t)(b*LSEQ + lt*64 + li))*(3*HDIM) + 2*HDIM + h*DHEAD + di;
    ushort4 v = *(const ushort4*)src;
    *(ushort4*)&tile[li][di] = v;
  }
  __syncthreads();
  u16* dst = Vt + ((size_t)(b*NHEAD + h))*DHEAD*LSEQ + lt*64;
#pragma unroll
  for (int it = 0; it < 32; it++) {
    int idx = it*256 + t;
    int lo = idx & 63, dd = idx >> 6;
    dst[(size_t)dd*LSEQ + lo] = tile[lo][dd];
  }
}

// ---------------- flash attention: no-max softmax (rmsnorm bounds logits) ----------------
// |q|=|k|=sqrt(128)*O(1) after rmsnorm => |logit| <~ 34; exp2 range-safe in fp32.
#define SC2 0.12753329583f   // (1/sqrt(128)) * log2(e)
__global__ __launch_bounds__(256, 2) void k_attn(const u16* __restrict__ Q,
                                                 const u16* __restrict__ Kc,
                                                 const u16* __restrict__ Vt,
                                                 u16* __restrict__ cat) {
  __shared__ u16 Ks[2*64*128];   // 32 KB dbuf
  __shared__ u16 Vs[2*128*64];   // 32 KB dbuf
  __shared__ u16 Ps[64*88];      // per-wave private rows
  int bid = blockIdx.x;
  int bh = bid & 31, qt = bid >> 5;
  int h = bh & 15, b = bh >> 4;
  int t = threadIdx.x, wave = t >> 6, lane = t & 63;
  int fm = lane & 15, fq = lane >> 4;
  int r8 = lane >> 3, c8 = lane & 7;
  const u16* Qg = Q  + (((size_t)(b*NHEAD + h))*LSEQ + qt*64) * DHEAD;
  const u16* Kg = Kc + ((size_t)(b*NHEAD + h))*LSEQ * DHEAD;
  const u16* Vg = Vt + ((size_t)(b*NHEAD + h))*DHEAD*LSEQ;
  short8 aq[4];
#pragma unroll
  for (int ks = 0; ks < 4; ks++)
    aq[ks] = *(const short8*)(Qg + (size_t)(wave*16 + fm)*DHEAD + ks*32 + fq*8);
#pragma unroll
  for (int i = 0; i < 4; i++) {
    int row = wave*16 + i*4;
    ASYNC16(Kg + (size_t)(row + fq)*DHEAD + fm*8, &Ks[row*DHEAD]);
    int vrow = wave*32 + i*8;
    ASYNC16(Vg + (size_t)(vrow + r8)*LSEQ + c8*8, &Vs[vrow*64]);
  }
  const f32x4 fzero = {0.f, 0.f, 0.f, 0.f};
  f32x4 o[8];
#pragma unroll
  for (int i = 0; i < 8; i++) o[i] = fzero;
  float lsum[4] = {0.f, 0.f, 0.f, 0.f};
  for (int kt = 0; kt < 32; kt++) {
    int cur = kt & 1;
    __syncthreads();   // drains prev-iter staging (issued a full iter ago)
    if (kt < 31) {
      int off = (cur ^ 1) * 8192;
      const u16* Kt_ = Kg + (size_t)(kt+1)*64*DHEAD;
      const u16* Vt_ = Vg + (kt+1)*64;
#pragma unroll
      for (int i = 0; i < 4; i++) {
        int row = wave*16 + i*4;
        ASYNC16(Kt_ + (size_t)(row + fq)*DHEAD + fm*8, &Ks[off + row*DHEAD]);
        int vrow = wave*32 + i*8;
        ASYNC16(Vt_ + (size_t)(vrow + r8)*LSEQ + c8*8, &Vs[off + vrow*64]);
      }
    }
    const u16* Kb = &Ks[cur*8192];
    const u16* Vb = &Vs[cur*8192];
    f32x4 s[4];
#pragma unroll
    for (int nt = 0; nt < 4; nt++) s[nt] = fzero;
#pragma unroll
    for (int ks = 0; ks < 4; ks++) {
#pragma unroll
      for (int nt = 0; nt < 4; nt++) {
        short8 bk = *(const short8*)&Kb[(nt*16 + fm)*DHEAD + ks*32 + fq*8];
        s[nt] = __builtin_amdgcn_mfma_f32_16x16x32_bf16(aq[ks], bk, s[nt], 0, 0, 0);
      }
    }
    // p = 2^(s*SC2); accumulate per-lane row sums, no max / no rescale
#pragma unroll
    for (int nt = 0; nt < 4; nt++)
#pragma unroll
      for (int r = 0; r < 4; r++) {
        float p = exp2f(s[nt][r] * SC2);
        s[nt][r] = p;
        lsum[r] += p;
      }
#pragma unroll
    for (int nt = 0; nt < 4; nt++)
#pragma unroll
      for (int r = 0; r < 4; r++)
        Ps[(wave*16 + fq*4 + r)*88 + nt*16 + fm] = f2bf_trunc(s[nt][r]);
    asm volatile("s_waitcnt lgkmcnt(0)" ::: "memory");
#pragma unroll
    for (int ks2 = 0; ks2 < 2; ks2++) {
      short8 ap = *(const short8*)&Ps[(wave*16 + fm)*88 + ks2*32 + fq*8];
#pragma unroll
      for (int nt = 0; nt < 8; nt++) {
        short8 bv = *(const short8*)&Vb[(nt*16 + fm)*64 + ks2*32 + fq*8];
        o[nt] = __builtin_amdgcn_mfma_f32_16x16x32_bf16(ap, bv, o[nt], 0, 0, 0);
      }
    }
  }
  // single final reduction of row sums over the 16 column-lanes
#pragma unroll
  for (int r = 0; r < 4; r++) {
#pragma unroll
    for (int o2 = 8; o2 >= 1; o2 >>= 1) lsum[r] += __shfl_xor(lsum[r], o2, 64);
  }
#pragma unroll
  for (int nt = 0; nt < 8; nt++) {
#pragma unroll
    for (int r = 0; r < 4; r++) {
      int l = qt*64 + wave*16 + fq*4 + r;
      int d = nt*16 + fm;
      float v = o[nt][r] / lsum[r];
      cat[((size_t)(b*LSEQ + l))*NC + h*DHEAD + d] = f2bf(v);
    }
  }
}

// ---------------- launch ----------------
extern "C" void kernel_launch(void* const* d_in, const int* in_sizes, int n_in,
                              void* d_out, int out_size, void* d_ws, size_t ws_size,
                              hipStream_t stream) {
  const float* x       = (const float*)d_in[0];
  const float* vec     = (const float*)d_in[1];
  const float* pe      = (const float*)d_in[2];
  const float* mod_w   = (const float*)d_in[3];
  const float* mod_b   = (const float*)d_in[4];
  const float* lin1_w  = (const float*)d_in[5];
  const float* lin1_b  = (const float*)d_in[6];
  const float* lin2_w  = (const float*)d_in[7];
  const float* lin2_b  = (const float*)d_in[8];
  const float* q_scale = (const float*)d_in[9];
  const float* k_scale = (const float*)d_in[10];
  char* ws = (char*)d_ws;

  // workspace layout, high-water ~210 MB
  float* modv = (float*)(ws + 0);                 //  48 KB
  u16* xmod  = (u16*)(ws + 65536ULL);             //  16.8 MB
  u16* qkv   = (u16*)(ws + 16842752ULL);          //  50.3 MB (dead after qk/vt)
  u16* w2    = (u16*)(ws + 16842752ULL);          //  aliases qkv (written after qk/vt)
  u16* cat   = (u16*)(ws + 67174400ULL);          //  83.9 MB
  u16* w1    = (u16*)(ws + 151060480ULL);         //  58.7 MB (dead after GEMM1)
  u16* Qb    = (u16*)(ws + 151060480ULL);         //  aliases w1
  u16* Kb    = (u16*)(ws + 167837696ULL);
  u16* Vtb   = (u16*)(ws + 184614912ULL);         //  end at ~201.4 MB

  k_mod<<<dim3(3*HDIM), dim3(256), 0, stream>>>(vec, mod_w, mod_b, modv);
  k_cvt<<<dim3(4096), dim3(256), 0, stream>>>((const float4*)lin1_w, (ushort4*)w1, (N1*HDIM)/4);
  k_ln<<<dim3(4096), dim3(256), 0, stream>>>(x, modv, xmod);
  k_gemm1<<<dim3(32*112), dim3(256), 0, stream>>>(xmod, w1, lin1_b, qkv, cat);
  k_qk<<<dim3(4096), dim3(256), 0, stream>>>(qkv, pe, q_scale, k_scale, Qb, Kb);
  k_vt<<<dim3(1024), dim3(256), 0, stream>>>(qkv, Vtb);
  k_cvt<<<dim3(4096), dim3(256), 0, stream>>>((const float4*)lin2_w, (ushort4*)w2, (HDIM*NC)/4);
  k_attn<<<dim3(1024), dim3(256), 0, stream>>>(Qb, Kb, Vtb, cat);
  k_gemm2<<<dim3(32*16), dim3(256), 0, stream>>>(cat, w2, lin2_b, x, modv, (float*)d_out);
}